// Round 12
// baseline (229.984 us; speedup 1.0000x reference)
//
#include <hip/hip_runtime.h>
#include <hip/hip_bf16.h>

// B=8, T=4096, C=384, H=64 causal single-head attention. fp32 in/out.
//
// Round-24: attn L1-volume halving (32 Q-rows per wave per K-tile).
// r23 post-mortem: 512x512 grid gave each CU one big + one small block ->
// big block ran alone at 2x serial depth (55.5us); reverted grid.
// Model revision: r21 accounting closes as L1-BANDWIDTH bound: 16 waves x
// 16.25 tiles x 16KB = 4.2 MB/CU of L1->VGPR K/V traffic (~66k cy at
// ~64B/cy) + 32k cy VALU ~= 108k measured. Every wave redundantly loads the
// full K/V tile. Fix: 16 waves = 8 k-groups x 2 row-halves; wave (g,rh)
// owns rows rh*32..rh*32+31 as two sequential 16-row rowsets A/B, k-tiles
// t = 8j+g -> each K/V load feeds 2x MFMA work, L1 volume halves to 2.1MB.
// Per tile: QK-A, QK-B (ka dies), clobber, vb load, softmaxA+PV-A,
// softmaxB+PV-B. Acc = scA+scB+oA+oB = 64; arch ~60 -> ~124 <= 128 cap.
// Merge: 8-way tree (3 rounds, 4 LDS bufs, ~66KB). 2 phases as r21.
// qkv/wtrans frozen (r22). No-spill gate: FETCH ~6.2MB, WRITE ~8.2MB.
//
//  k_frag layout: [blk64][st][c8=h/8][i=m][j=h%8], row m of st holds
//                 K row s = 32*(st>>1) + 8*(m>>2) + 4*(st&1) + (m&3)
//  vt_frag layout: [st=row/64][dt=d/16][sc=s%64/8][i=d%16][j=s%8]

typedef __bf16 bf16x8 __attribute__((ext_vector_type(8)));
typedef float  f32x4  __attribute__((ext_vector_type(4)));

#define BB   8
#define TT   4096
#define CC   384
#define HH   64
#define NROW (BB*TT)       // 32768
// C^-0.5 * log2(e): fold softmax scale + exp2 conversion into q at projection
#define QSCALE (0.05103103630798288f * 1.4426950408889634f)

#if __has_builtin(__builtin_amdgcn_exp2f)
#define EXP2(x) __builtin_amdgcn_exp2f(x)
#else
#define EXP2(x) exp2f(x)
#endif

__device__ __forceinline__ unsigned short f2bf(float f) {
    __bf16 h = (__bf16)f;
    return __builtin_bit_cast(unsigned short, h);
}

// ---------------------------------------------------------------- kernel 1
// Wt[mat][h][c] = bf16(W[mat][c][h]), via LDS tile (coalesced both sides).
__global__ __launch_bounds__(256) void wtrans_kernel(
        const float* __restrict__ Wk,
        const float* __restrict__ Wq,
        const float* __restrict__ Wv,
        unsigned short* __restrict__ Wt) {
    __shared__ __align__(16) unsigned short tile[64][72];
    const float* Wm = (blockIdx.y == 0) ? Wk : ((blockIdx.y == 1) ? Wq : Wv);
    unsigned short* Wtm = Wt + blockIdx.y * (HH * CC);
    const int c0 = blockIdx.x * 64;
#pragma unroll
    for (int i = 0; i < 16; ++i) {
        int id = threadIdx.x + i * 256;         // 0..4095
        int c = id >> 6, h = id & 63;
        tile[c][h] = f2bf(Wm[(c0 + c) * HH + h]);   // coalesced read
    }
    __syncthreads();
#pragma unroll
    for (int i = 0; i < 16; ++i) {
        int id = threadIdx.x + i * 256;
        int h = id >> 6, c = id & 63;
        Wtm[h * CC + c0 + c] = tile[c][h];      // coalesced write
    }
}

// ---------------------------------------------------------------- kernel 2
// QKV projection (frozen at r22): 1024 blocks x 256 thr; x staged via
// single-phase global_load_lds; Wt depth-12 register pipeline with issue-
// position clobber. ~47us across six structural variants.
__global__ __launch_bounds__(256, 1) void qkv_kernel(
        const float* __restrict__ x,
        const unsigned short* __restrict__ Wt,     // [3][64][384] bf16
        unsigned short* __restrict__ q_ws,         // [32768][64] row-major, pre-scaled
        unsigned short* __restrict__ k_ws,         // fragment layout (permuted)
        unsigned short* __restrict__ vt_ws) {      // fragment layout
    __shared__ __align__(16) float xs[6][32][64];               // 49152 B
    __shared__ __align__(16) unsigned short vtile[64][40];      //  5120 B

    const int lane = threadIdx.x & 63;
    const int wv   = threadIdx.x >> 6;     // 0..3
    const int rt   = wv & 1;               // row-tile (16 rows)
    const int hh   = wv >> 1;              // h-half (2 nt)
    const int l15  = lane & 15;
    const int quad = lane >> 4;
    const int rb   = blockIdx.x * 32;
    const int ntb  = hh * 2;               // first of this wave's two nt

#pragma unroll
    for (int kk = 0; kk < 6; ++kk) {
#pragma unroll
        for (int j = 0; j < 2; ++j) {
            const int r0 = wv * 8 + j * 4;                 // instr's first row
            const int r  = r0 + quad;                      // this lane's row
            const int ch = l15 ^ (r & 7);                  // swizzled src chunk
            const float* src = x + (long)(rb + r) * CC + kk * 64 + ch * 4;
            float* dst = &xs[kk][r0][0];                   // linear: +lane*16B
            __builtin_amdgcn_global_load_lds(
                (const __attribute__((address_space(1))) unsigned int*)src,
                (__attribute__((address_space(3))) unsigned int*)dst,
                16, 0, 0);
        }
    }

    bf16x8 bf[2][12];
    auto loadW = [&](int kk, bf16x8* dst) {
#pragma unroll
        for (int m = 0; m < 3; ++m)
#pragma unroll
            for (int n = 0; n < 2; ++n)
#pragma unroll
                for (int h01 = 0; h01 < 2; ++h01)
                    dst[m * 4 + n * 2 + h01] = *reinterpret_cast<const bf16x8*>(
                        Wt + m * (HH * CC) + ((ntb + n) * 16 + l15) * CC
                          + kk * 64 + h01 * 32 + quad * 8);
    };
    loadW(0, bf[0]);

    f32x4 acc[3][2];
    const f32x4 zero = {0.f, 0.f, 0.f, 0.f};
#pragma unroll
    for (int m = 0; m < 3; ++m)
#pragma unroll
        for (int n = 0; n < 2; ++n) acc[m][n] = zero;

    const int rloc = rt * 16 + l15;        // A-frag row (local)
    const int rx7  = rloc & 7;

    __asm volatile("s_waitcnt vmcnt(0)" ::: "memory");  // x DMA + bf[0]
    __syncthreads();

#pragma unroll
    for (int kk = 0; kk < 6; ++kk) {
        if (kk < 5) {
            loadW(kk + 1, bf[(kk + 1) & 1]);   // 12 loads in flight
            __asm volatile("" ::: "memory");   // pin issue position
        }
#pragma unroll
        for (int h01 = 0; h01 < 2; ++h01) {
            const int chb = 8 * h01 + 2 * quad;
            const f32x4 xa = *reinterpret_cast<const f32x4*>(
                &xs[kk][rloc][((chb) ^ rx7) * 4]);
            const f32x4 xb = *reinterpret_cast<const f32x4*>(
                &xs[kk][rloc][((chb + 1) ^ rx7) * 4]);
            bf16x8 a;
#pragma unroll
            for (int e = 0; e < 4; ++e) {
                a[e]     = (__bf16)xa[e];
                a[4 + e] = (__bf16)xb[e];
            }
#pragma unroll
            for (int m = 0; m < 3; ++m)
#pragma unroll
                for (int n = 0; n < 2; ++n)
                    acc[m][n] = __builtin_amdgcn_mfma_f32_16x16x32_bf16(
                        a, bf[kk & 1][m * 4 + n * 2 + h01], acc[m][n], 0, 0, 0);
        }
    }

#pragma unroll
    for (int n = 0; n < 2; ++n) {
        const int nt = ntb + n;
        const int h  = nt * 16 + l15;
        const int c8 = h >> 3;
        const int jj = h & 7;
#pragma unroll
        for (int r = 0; r < 4; ++r) {
            const int gr = rb + rt * 16 + quad * 4 + r;
            const int s   = gr & 63;
            const int stp = ((s >> 4) & 2) + ((s >> 2) & 1); // 2*(s>>5)+bit2
            const int ip  = ((s >> 1) & 12) + (s & 3);       // 4*((s>>3)&3)+(s&3)
            k_ws[(long)(gr >> 6) * 4096 + stp * 1024 + c8 * 128 + ip * 8 + jj]
                = f2bf(acc[0][n][r]);
            q_ws[gr * HH + h] = f2bf(acc[1][n][r] * QSCALE);
            vtile[h][rt * 16 + quad * 4 + r] = f2bf(acc[2][n][r]);
        }
    }
    __syncthreads();
    {
        const int id  = threadIdx.x;               // 0..255
        const int dt  = id >> 6, scl = (id >> 4) & 3, ii = id & 15;
        const int sc  = scl + ((rb >> 3) & 4);
        unsigned short* dst = vt_ws + (long)(rb >> 6) * 4096
                              + (dt * 8 + sc) * 128 + ii * 8;
        *reinterpret_cast<uint4*>(dst) =
            *reinterpret_cast<const uint4*>(&vtile[dt * 16 + ii][scl * 8]);
    }
}

// ---------------------------------------------------------------- kernel 3
// Flash attention. 256 blocks x 1024 thr; block (p,b) does q-tile 63-p then
// p. 16 waves = 8 k-groups x 2 row-halves; wave (g,rh) covers rows
// rh*32..rh*32+31 as rowsets A/B for k-tiles t = 8j+g (each K/V load feeds
// 2x MFMA work -> L1 volume halved). P in registers; defer-max (THR=8);
// per-quad lsum until merge. 8-way tree merge (3 rounds, 4 LDS buffers).
__global__ __launch_bounds__(1024, 4) void attn_kernel(
        const unsigned short* __restrict__ q_ws,
        const unsigned short* __restrict__ k_ws,   // permuted fragment layout
        const unsigned short* __restrict__ vt_ws,  // fragment layout
        float* __restrict__ out) {
    __shared__ __align__(16) float xbuf[4][64][65];              // 66560 B
    __shared__ float mxb[4][64], lxb[4][64];                     //  2048 B

    const int lane = threadIdx.x & 63;
    const int wv16 = threadIdx.x >> 6;     // 0..15
    const int g    = wv16 >> 1;            // k-group 0..7
    const int rh   = wv16 & 1;             // row-half 0/1
    const int l15  = lane & 15;
    const int quad = lane >> 4;

    const int bid = blockIdx.x;
    const int b   = bid & 7;               // batch <-> XCD affinity
    const int p   = bid >> 3;              // 0..31

    const f32x4 zero = {0.f, 0.f, 0.f, 0.f};

    // softmax + PV for one rowset (sc consumed, o/m/l updated)
    auto sm_pv = [&](f32x4* sc, f32x4* o, float& m, float& l,
                     const bf16x8* vb0, const bf16x8* vb1) {
        float mloc = -1e30f;
#pragma unroll
        for (int st = 0; st < 4; ++st)
#pragma unroll
            for (int r = 0; r < 4; ++r) mloc = fmaxf(mloc, sc[st][r]);
        mloc = fmaxf(mloc, __shfl_xor(mloc, 16));
        mloc = fmaxf(mloc, __shfl_xor(mloc, 32));

        if (!__all(mloc <= m + 8.0f)) {      // defer-max THR=8 (exp2 domain)
            const float mnew = fmaxf(m, mloc);
            const float alpha = EXP2(m - mnew);
            l *= alpha;
            float ar[4];
#pragma unroll
            for (int r = 0; r < 4; ++r) ar[r] = __shfl(alpha, quad * 4 + r);
#pragma unroll
            for (int dt = 0; dt < 4; ++dt)
#pragma unroll
                for (int r = 0; r < 4; ++r) o[dt][r] *= ar[r];
            m = mnew;
        }

        float psum = 0.f;
#pragma unroll
        for (int st = 0; st < 4; ++st)
#pragma unroll
            for (int r = 0; r < 4; ++r) {
                float pv = EXP2(sc[st][r] - m);
                psum += pv;
                sc[st][r] = pv;
            }
        l += psum;

        bf16x8 pf0, pf1;
#pragma unroll
        for (int r = 0; r < 4; ++r) {
            pf0[r]     = (__bf16)sc[0][r];
            pf0[4 + r] = (__bf16)sc[1][r];
            pf1[r]     = (__bf16)sc[2][r];
            pf1[4 + r] = (__bf16)sc[3][r];
        }
        __builtin_amdgcn_s_setprio(1);
#pragma unroll
        for (int dt = 0; dt < 4; ++dt) {
            o[dt] = __builtin_amdgcn_mfma_f32_16x16x32_bf16(pf0, vb0[dt], o[dt], 0, 0, 0);
            o[dt] = __builtin_amdgcn_mfma_f32_16x16x32_bf16(pf1, vb1[dt], o[dt], 0, 0, 0);
        }
        __builtin_amdgcn_s_setprio(0);
    };

    // one k-tile: QK for both rowsets off one ka load, then vb, then sm+PV x2
    auto do_tile = [&](int t, int qt, int qrowA,
                       const bf16x8& qfA0, const bf16x8& qfA1,
                       const bf16x8& qfB0, const bf16x8& qfB1,
                       f32x4* oA, f32x4* oB,
                       float& mA, float& lA, float& mB, float& lB) {
        const int s0 = t * 64;
        const unsigned short* ktile = k_ws + ((long)((b * TT + s0) >> 4)) * 1024;
        const unsigned short* vtile = vt_ws + ((long)((b * TT + s0) >> 6)) * 4096;

        bf16x8 ka0[4], ka1[4];
#pragma unroll
        for (int st = 0; st < 4; ++st) {
            ka0[st] = *reinterpret_cast<const bf16x8*>(
                ktile + ((st * 8 + quad) * 16 + l15) * 8);
            ka1[st] = *reinterpret_cast<const bf16x8*>(
                ktile + ((st * 8 + 4 + quad) * 16 + l15) * 8);
        }

        f32x4 scA[4], scB[4];
        __builtin_amdgcn_s_setprio(1);
#pragma unroll
        for (int st = 0; st < 4; ++st) {
            f32x4 z = zero;
            z = __builtin_amdgcn_mfma_f32_16x16x32_bf16(ka0[st], qfA0, z, 0, 0, 0);
            z = __builtin_amdgcn_mfma_f32_16x16x32_bf16(ka1[st], qfA1, z, 0, 0, 0);
            scA[st] = z;
        }
#pragma unroll
        for (int st = 0; st < 4; ++st) {
            f32x4 z = zero;
            z = __builtin_amdgcn_mfma_f32_16x16x32_bf16(ka0[st], qfB0, z, 0, 0, 0);
            z = __builtin_amdgcn_mfma_f32_16x16x32_bf16(ka1[st], qfB1, z, 0, 0, 0);
            scB[st] = z;
        }
        __builtin_amdgcn_s_setprio(0);
        // ka dead; keep vb loads from hoisting above (reuse ka's registers)
        __asm volatile("" ::: "memory");

        bf16x8 vb0[4], vb1[4];
#pragma unroll
        for (int dt = 0; dt < 4; ++dt) {
            vb0[dt] = *reinterpret_cast<const bf16x8*>(
                vtile + dt * 1024 + quad * 128 + l15 * 8);
            vb1[dt] = *reinterpret_cast<const bf16x8*>(
                vtile + dt * 1024 + (4 + quad) * 128 + l15 * 8);
        }

        if (t == qt) {                    // causal mask, diagonal tile only
            // permuted row map: s_local = 32*(st>>1) + 8*quad + 4*(st&1) + r
#pragma unroll
            for (int st = 0; st < 4; ++st)
#pragma unroll
                for (int r = 0; r < 4; ++r) {
                    int sg = s0 + ((st >> 1) << 5) + (quad << 3)
                               + ((st & 1) << 2) + r;
                    if (sg > qrowA)      scA[st][r] = -1e30f;
                    if (sg > qrowA + 16) scB[st][r] = -1e30f;
                }
        }

        sm_pv(scA, oA, mA, lA, vb0, vb1);
        sm_pv(scB, oB, mB, lB, vb0, vb1);
    };

    // -------- one full phase for q-tile qt --------
    auto run_phase = [&](int qt) {
        const int qrowA = qt * 64 + rh * 32 + l15;
        const unsigned short* qbA = q_ws + (b * TT + qrowA) * HH;
        const unsigned short* qbB = qbA + 16 * HH;
        const bf16x8 qfA0 = *reinterpret_cast<const bf16x8*>(qbA + quad * 8);
        const bf16x8 qfA1 = *reinterpret_cast<const bf16x8*>(qbA + 32 + quad * 8);
        const bf16x8 qfB0 = *reinterpret_cast<const bf16x8*>(qbB + quad * 8);
        const bf16x8 qfB1 = *reinterpret_cast<const bf16x8*>(qbB + 32 + quad * 8);

        f32x4 oA[4], oB[4];
#pragma unroll
        for (int dt = 0; dt < 4; ++dt) { oA[dt] = zero; oB[dt] = zero; }
        float mA = -1e30f, lA = 0.f, mB = -1e30f, lB = 0.f;

        for (int t = g; t <= qt; t += 8)
            do_tile(t, qt, qrowA, qfA0, qfA1, qfB0, qfB1, oA, oB, mA, lA, mB, lB);

        // complete deferred quad-reduction of lsum
        lA += __shfl_xor(lA, 16); lA += __shfl_xor(lA, 32);
        lB += __shfl_xor(lB, 16); lB += __shfl_xor(lB, 32);

        // -------- 8-way tree merge: 3 rounds --------
#pragma unroll
        for (int round = 0; round < 3; ++round) {
            const int step = 1 << round;
            const bool active = (g & (step - 1)) == 0;
            const bool writer = active && (g & step);
            const int bx = g >> (round + 1);
            __syncthreads();
            if (writer) {
                if (quad == 0) {
                    mxb[bx][rh * 32 + l15]      = mA; lxb[bx][rh * 32 + l15]      = lA;
                    mxb[bx][rh * 32 + 16 + l15] = mB; lxb[bx][rh * 32 + 16 + l15] = lB;
                }
#pragma unroll
                for (int dt = 0; dt < 4; ++dt)
#pragma unroll
                    for (int r = 0; r < 4; ++r) {
                        xbuf[bx][rh * 32 + quad * 4 + r][dt * 16 + l15]      = oA[dt][r];
                        xbuf[bx][rh * 32 + 16 + quad * 4 + r][dt * 16 + l15] = oB[dt][r];
                    }
            }
            __syncthreads();
            if (active && !writer) {
                // rowset A
#pragma unroll
                for (int r = 0; r < 4; ++r) {
                    const int row = rh * 32 + quad * 4 + r;
                    const float m0r = __shfl(mA, quad * 4 + r);
                    const float m1r = mxb[bx][row];
                    const float ms  = fmaxf(m0r, m1r);
                    const float w0  = EXP2(m0r - ms);
                    const float w1  = EXP2(m1r - ms);
#pragma unroll
                    for (int dt = 0; dt < 4; ++dt)
                        oA[dt][r] = oA[dt][r] * w0 + xbuf[bx][row][dt * 16 + l15] * w1;
                }
                {
                    const float m1l = mxb[bx][rh * 32 + l15];
                    const float msl = fmaxf(mA, m1l);
                    lA = EXP2(mA - msl) * lA + EXP2(m1l - msl) * lxb[bx][rh * 32 + l15];
                    mA = msl;
                }
                // rowset B
#pragma unroll
                for (int r = 0; r < 4; ++r) {
                    const int row = rh * 32 + 16 + quad * 4 + r;
                    const float m0r = __shfl(mB, quad * 4 + r);
                    const float m1r = mxb[bx][row];
                    const float ms  = fmaxf(m0r, m1r);
                    const float w0  = EXP2(m0r - ms);
                    const float w1  = EXP2(m1r - ms);
#pragma unroll
                    for (int dt = 0; dt < 4; ++dt)
                        oB[dt][r] = oB[dt][r] * w0 + xbuf[bx][row][dt * 16 + l15] * w1;
                }
                {
                    const float m1l = mxb[bx][rh * 32 + 16 + l15];
                    const float msl = fmaxf(mB, m1l);
                    lB = EXP2(mB - msl) * lB + EXP2(m1l - msl) * lxb[bx][rh * 32 + 16 + l15];
                    mB = msl;
                }
            }
        }

        if (g == 0) {
            float rlA[4], rlB[4];
#pragma unroll
            for (int r = 0; r < 4; ++r) {
                rlA[r] = 1.0f / __shfl(lA, quad * 4 + r);
                rlB[r] = 1.0f / __shfl(lB, quad * 4 + r);
            }
            const int orowA = qt * 64 + rh * 32 + quad * 4;
#pragma unroll
            for (int dt = 0; dt < 4; ++dt)
#pragma unroll
                for (int r = 0; r < 4; ++r) {
                    out[(long)(b * TT + orowA + r) * HH + dt * 16 + l15]
                        = oA[dt][r] * rlA[r];
                    out[(long)(b * TT + orowA + 16 + r) * HH + dt * 16 + l15]
                        = oB[dt][r] * rlB[r];
                }
        }
        __syncthreads();   // buffers reusable by next phase
    };

    run_phase(63 - p);     // phase A
    run_phase(p);          // phase B
}

// ---------------------------------------------------------------- launch
extern "C" void kernel_launch(void* const* d_in, const int* in_sizes, int n_in,
                              void* d_out, int out_size, void* d_ws, size_t ws_size,
                              hipStream_t stream) {
    const float* x  = (const float*)d_in[0];
    const float* Wk = (const float*)d_in[1];
    const float* Wq = (const float*)d_in[2];
    const float* Wv = (const float*)d_in[3];
    float* out = (float*)d_out;

    char* ws = (char*)d_ws;
    unsigned short* Wt    = (unsigned short*)(ws);                         // 147456 B
    unsigned short* q_ws  = (unsigned short*)(ws + 147456);                // 4 MiB
    unsigned short* k_ws  = (unsigned short*)(ws + 147456 + 4194304);      // 4 MiB
    unsigned short* vt_ws = (unsigned short*)(ws + 147456 + 2 * 4194304);  // 4 MiB

    wtrans_kernel<<<dim3(6, 3), 256, 0, stream>>>(Wk, Wq, Wv, Wt);
    qkv_kernel<<<NROW / 32, 256, 0, stream>>>(x, Wt, q_ws, k_ws, vt_ws);
    attn_kernel<<<(TT / 128) * BB, 1024, 0, stream>>>(q_ws, k_ws, vt_ws, out);
}

// Round 13
// 160.147 us; speedup vs baseline: 1.4361x; 1.4361x over previous
//
#include <hip/hip_runtime.h>
#include <hip/hip_bf16.h>

// B=8, T=4096, C=384, H=64 causal single-head attention. fp32 in/out.
//
// Round-25: REVERT to round-22 (best measured: 160.45us total; attn 45.5,
// qkv 46.7). r24 post-mortem: third register-wall spill (doubled rowset
// accumulators = 64 acc regs + arch state > 128 unified cap; FETCH 72MB /
// WRITE 272MB scratch, attn 125us). The attn structural space is closed by
// three independent walls, each confirmed >=2x:
//  (1) 128-unified-reg cap at 16-wave blocks: ANY added in-flight state
//      spills (r19 ping-pong, r20 in-place prefetch, r24 rowset-doubling).
//  (2) No sub-block barrier: K/V LDS de-duplication needs group-scope sync
//      (block barriers reintroduce the convoy; drifting dbuf races).
//  (3) Load balance: smaller blocks lose the balanced 16-wave schedule
//      (r14 64us, r23 55us).
// Wins that stuck were zero-register chain cuts only: in-register P (r15,
// -5us), defer-max + per-quad lsum (r21, -5us). qkv frozen: ~47us invariant
// across six structural variants, all pipes <11%.
//
//  k_frag layout: [blk64][st][c8=h/8][i=m][j=h%8], row m of st holds
//                 K row s = 32*(st>>1) + 8*(m>>2) + 4*(st&1) + (m&3)
//  vt_frag layout: [st=row/64][dt=d/16][sc=s%64/8][i=d%16][j=s%8]

typedef __bf16 bf16x8 __attribute__((ext_vector_type(8)));
typedef float  f32x4  __attribute__((ext_vector_type(4)));

#define BB   8
#define TT   4096
#define CC   384
#define HH   64
#define NROW (BB*TT)       // 32768
// C^-0.5 * log2(e): fold softmax scale + exp2 conversion into q at projection
#define QSCALE (0.05103103630798288f * 1.4426950408889634f)

#if __has_builtin(__builtin_amdgcn_exp2f)
#define EXP2(x) __builtin_amdgcn_exp2f(x)
#else
#define EXP2(x) exp2f(x)
#endif

__device__ __forceinline__ unsigned short f2bf(float f) {
    __bf16 h = (__bf16)f;
    return __builtin_bit_cast(unsigned short, h);
}

// ---------------------------------------------------------------- kernel 1
// Wt[mat][h][c] = bf16(W[mat][c][h]), via LDS tile (coalesced both sides).
__global__ __launch_bounds__(256) void wtrans_kernel(
        const float* __restrict__ Wk,
        const float* __restrict__ Wq,
        const float* __restrict__ Wv,
        unsigned short* __restrict__ Wt) {
    __shared__ __align__(16) unsigned short tile[64][72];
    const float* Wm = (blockIdx.y == 0) ? Wk : ((blockIdx.y == 1) ? Wq : Wv);
    unsigned short* Wtm = Wt + blockIdx.y * (HH * CC);
    const int c0 = blockIdx.x * 64;
#pragma unroll
    for (int i = 0; i < 16; ++i) {
        int id = threadIdx.x + i * 256;         // 0..4095
        int c = id >> 6, h = id & 63;
        tile[c][h] = f2bf(Wm[(c0 + c) * HH + h]);   // coalesced read
    }
    __syncthreads();
#pragma unroll
    for (int i = 0; i < 16; ++i) {
        int id = threadIdx.x + i * 256;
        int h = id >> 6, c = id & 63;
        Wtm[h * CC + c0 + c] = tile[c][h];      // coalesced write
    }
}

// ---------------------------------------------------------------- kernel 2
// QKV projection (frozen): [32768,384]x[384,64] x3 with 16x16x32 bf16 MFMA.
// 1024 blocks x 256 thr; block = 32 rows. 4 waves = 2 row-tiles x 2 h-halves.
// ALL of x staged fp32 into LDS by 12 global_load_lds per wave (one vmcnt +
// one barrier). Wt consumed through a depth-12 register pipeline: bf[2][12],
// chunk kk+1 prefetched while chunk kk computes; asm memory fence after each
// prefetch pins the loads at issue position.
__global__ __launch_bounds__(256, 1) void qkv_kernel(
        const float* __restrict__ x,
        const unsigned short* __restrict__ Wt,     // [3][64][384] bf16
        unsigned short* __restrict__ q_ws,         // [32768][64] row-major, pre-scaled
        unsigned short* __restrict__ k_ws,         // fragment layout (permuted)
        unsigned short* __restrict__ vt_ws) {      // fragment layout
    // xs[chunk][local row][64 floats]; 16B slot p of (chunk,row) holds global
    // sub-chunk p ^ (row&7). 48 KB, chunk-major so each 1KB DMA instruction
    // (4 rows x 256B) is contiguous.
    __shared__ __align__(16) float xs[6][32][64];               // 49152 B
    __shared__ __align__(16) unsigned short vtile[64][40];      //  5120 B

    const int lane = threadIdx.x & 63;
    const int wv   = threadIdx.x >> 6;     // 0..3
    const int rt   = wv & 1;               // row-tile (16 rows)
    const int hh   = wv >> 1;              // h-half (2 nt)
    const int l15  = lane & 15;
    const int quad = lane >> 4;
    const int rb   = blockIdx.x * 32;
    const int ntb  = hh * 2;               // first of this wave's two nt

    // ---- stage ALL 6 chunks: 12 independent DMA instructions per wave ----
#pragma unroll
    for (int kk = 0; kk < 6; ++kk) {
#pragma unroll
        for (int j = 0; j < 2; ++j) {
            const int r0 = wv * 8 + j * 4;                 // instr's first row
            const int r  = r0 + quad;                      // this lane's row
            const int ch = l15 ^ (r & 7);                  // swizzled src chunk
            const float* src = x + (long)(rb + r) * CC + kk * 64 + ch * 4;
            float* dst = &xs[kk][r0][0];                   // linear: +lane*16B
            __builtin_amdgcn_global_load_lds(
                (const __attribute__((address_space(1))) unsigned int*)src,
                (__attribute__((address_space(3))) unsigned int*)dst,
                16, 0, 0);
        }
    }

    // ---- Wt register pipeline: 12 fragments per 64-col chunk ----
    bf16x8 bf[2][12];
    auto loadW = [&](int kk, bf16x8* dst) {
#pragma unroll
        for (int m = 0; m < 3; ++m)
#pragma unroll
            for (int n = 0; n < 2; ++n)
#pragma unroll
                for (int h01 = 0; h01 < 2; ++h01)
                    dst[m * 4 + n * 2 + h01] = *reinterpret_cast<const bf16x8*>(
                        Wt + m * (HH * CC) + ((ntb + n) * 16 + l15) * CC
                          + kk * 64 + h01 * 32 + quad * 8);
    };
    loadW(0, bf[0]);

    f32x4 acc[3][2];
    const f32x4 zero = {0.f, 0.f, 0.f, 0.f};
#pragma unroll
    for (int m = 0; m < 3; ++m)
#pragma unroll
        for (int n = 0; n < 2; ++n) acc[m][n] = zero;

    const int rloc = rt * 16 + l15;        // A-frag row (local)
    const int rx7  = rloc & 7;

    __asm volatile("s_waitcnt vmcnt(0)" ::: "memory");  // x DMA + bf[0]
    __syncthreads();

#pragma unroll
    for (int kk = 0; kk < 6; ++kk) {
        if (kk < 5) {
            loadW(kk + 1, bf[(kk + 1) & 1]);   // 12 loads in flight
            __asm volatile("" ::: "memory");   // pin issue position
        }
#pragma unroll
        for (int h01 = 0; h01 < 2; ++h01) {
            const int chb = 8 * h01 + 2 * quad;
            const f32x4 xa = *reinterpret_cast<const f32x4*>(
                &xs[kk][rloc][((chb) ^ rx7) * 4]);
            const f32x4 xb = *reinterpret_cast<const f32x4*>(
                &xs[kk][rloc][((chb + 1) ^ rx7) * 4]);
            bf16x8 a;
#pragma unroll
            for (int e = 0; e < 4; ++e) {
                a[e]     = (__bf16)xa[e];
                a[4 + e] = (__bf16)xb[e];
            }
#pragma unroll
            for (int m = 0; m < 3; ++m)
#pragma unroll
                for (int n = 0; n < 2; ++n)
                    acc[m][n] = __builtin_amdgcn_mfma_f32_16x16x32_bf16(
                        a, bf[kk & 1][m * 4 + n * 2 + h01], acc[m][n], 0, 0, 0);
        }
    }

    // Epilogue. C-layout: acc[m][n][r] = out[local row quad*4+r][h=(ntb+n)*16+l15]
#pragma unroll
    for (int n = 0; n < 2; ++n) {
        const int nt = ntb + n;
        const int h  = nt * 16 + l15;
        const int c8 = h >> 3;
        const int jj = h & 7;
#pragma unroll
        for (int r = 0; r < 4; ++r) {
            const int gr = rb + rt * 16 + quad * 4 + r;
            // k: permuted fragment position for local row s = gr & 63
            const int s   = gr & 63;
            const int stp = ((s >> 4) & 2) + ((s >> 2) & 1); // 2*(s>>5)+bit2
            const int ip  = ((s >> 1) & 12) + (s & 3);       // 4*((s>>3)&3)+(s&3)
            k_ws[(long)(gr >> 6) * 4096 + stp * 1024 + c8 * 128 + ip * 8 + jj]
                = f2bf(acc[0][n][r]);
            q_ws[gr * HH + h] = f2bf(acc[1][n][r] * QSCALE);
            vtile[h][rt * 16 + quad * 4 + r] = f2bf(acc[2][n][r]);
        }
    }
    __syncthreads();
    // vt fragment store: block covers sc-half (rb&32)>>3 of its 64-blk.
    {
        const int id  = threadIdx.x;               // 0..255
        const int dt  = id >> 6, scl = (id >> 4) & 3, ii = id & 15;
        const int sc  = scl + ((rb >> 3) & 4);
        unsigned short* dst = vt_ws + (long)(rb >> 6) * 4096
                              + (dt * 8 + sc) * 128 + ii * 8;
        *reinterpret_cast<uint4*>(dst) =
            *reinterpret_cast<const uint4*>(&vtile[dt * 16 + ii][scl * 8]);
    }
}

// ---------------------------------------------------------------- kernel 3
// Flash attention. 256 blocks x 1024 thr; block (p,b) does q-tile A=63-p
// then B=p (65 k-tiles constant). 16 waves = 4 groups x 4 waves; group g
// takes tiles t = 4j+g. Barrier-free k-loop, P entirely in registers
// (k_frag row permutation makes QK output == PV A-fragment).
// Softmax: defer-max (THR=8); lsum per-quad, reduced at merge entry.
// s_setprio(1) around QK/PV MFMA clusters (waves at independent phases).
__global__ __launch_bounds__(1024, 4) void attn_kernel(
        const unsigned short* __restrict__ q_ws,
        const unsigned short* __restrict__ k_ws,   // permuted fragment layout
        const unsigned short* __restrict__ vt_ws,  // fragment layout
        float* __restrict__ out) {
    __shared__ __align__(16) float xchg[64 * 65];                // 16640 B
    __shared__ float mx1[64], lx1[64];

    const int lane = threadIdx.x & 63;
    const int wv16 = threadIdx.x >> 6;     // 0..15
    const int grp  = wv16 >> 2;            // wave-group 0..3
    const int wg   = wv16 & 3;             // wave within group
    const int l15  = lane & 15;
    const int quad = lane >> 4;

    const int bid = blockIdx.x;
    const int b   = bid & 7;               // batch <-> XCD affinity
    const int p   = bid >> 3;              // 0..31

    const f32x4 zero = {0.f, 0.f, 0.f, 0.f};

    // -------- one k-tile of phase with q-tile `qt` --------
    auto do_tile = [&](int t, int qt, int qrow,
                       const bf16x8& qf0, const bf16x8& qf1,
                       f32x4* o, float& mprev, float& lsum) {
        const int s0 = t * 64;
        const unsigned short* ktile = k_ws + ((long)((b * TT + s0) >> 4)) * 1024;
        const unsigned short* vtile = vt_ws + ((long)((b * TT + s0) >> 6)) * 4096;

        bf16x8 ka0[4], ka1[4];
#pragma unroll
        for (int st = 0; st < 4; ++st) {
            ka0[st] = *reinterpret_cast<const bf16x8*>(
                ktile + ((st * 8 + quad) * 16 + l15) * 8);
            ka1[st] = *reinterpret_cast<const bf16x8*>(
                ktile + ((st * 8 + 4 + quad) * 16 + l15) * 8);
        }
        bf16x8 vb0[4], vb1[4];
#pragma unroll
        for (int dt = 0; dt < 4; ++dt) {
            vb0[dt] = *reinterpret_cast<const bf16x8*>(
                vtile + dt * 1024 + quad * 128 + l15 * 8);
            vb1[dt] = *reinterpret_cast<const bf16x8*>(
                vtile + dt * 1024 + (4 + quad) * 128 + l15 * 8);
        }

        f32x4 sc[4];
        __builtin_amdgcn_s_setprio(1);
#pragma unroll
        for (int st = 0; st < 4; ++st) {
            f32x4 z = zero;
            z = __builtin_amdgcn_mfma_f32_16x16x32_bf16(ka0[st], qf0, z, 0, 0, 0);
            z = __builtin_amdgcn_mfma_f32_16x16x32_bf16(ka1[st], qf1, z, 0, 0, 0);
            sc[st] = z;
        }
        __builtin_amdgcn_s_setprio(0);

        if (t == qt) {                    // causal mask, diagonal tile only
            // permuted row map: s_local = 32*(st>>1) + 8*quad + 4*(st&1) + r
#pragma unroll
            for (int st = 0; st < 4; ++st)
#pragma unroll
                for (int r = 0; r < 4; ++r) {
                    int sg = s0 + ((st >> 1) << 5) + (quad << 3)
                               + ((st & 1) << 2) + r;
                    if (sg > qrow) sc[st][r] = -1e30f;
                }
        }

        float mloc = -1e30f;
#pragma unroll
        for (int st = 0; st < 4; ++st)
#pragma unroll
            for (int r = 0; r < 4; ++r) mloc = fmaxf(mloc, sc[st][r]);
        mloc = fmaxf(mloc, __shfl_xor(mloc, 16));
        mloc = fmaxf(mloc, __shfl_xor(mloc, 32));

        // defer-max: keep old max when the tile max is within THR=8
        // (exp2 domain; P bounded by 2^8=256, bf16/fp32-safe).
        if (!__all(mloc <= mprev + 8.0f)) {
            const float mnew = fmaxf(mprev, mloc);
            const float alpha = EXP2(mprev - mnew);
            lsum *= alpha;
            float ar[4];
#pragma unroll
            for (int r = 0; r < 4; ++r) ar[r] = __shfl(alpha, quad * 4 + r);
#pragma unroll
            for (int dt = 0; dt < 4; ++dt)
#pragma unroll
                for (int r = 0; r < 4; ++r) o[dt][r] *= ar[r];
            mprev = mnew;
        }

        // exp2 against (possibly stale) mprev; lsum stays per-quad partial.
        float psum = 0.f;
#pragma unroll
        for (int st = 0; st < 4; ++st)
#pragma unroll
            for (int r = 0; r < 4; ++r) {
                float pv = EXP2(sc[st][r] - mprev);
                psum += pv;
                sc[st][r] = pv;
            }
        lsum += psum;

        // P in-register: sc[st][r] already in PV A-fragment order.
        bf16x8 pf0, pf1;
#pragma unroll
        for (int r = 0; r < 4; ++r) {
            pf0[r]     = (__bf16)sc[0][r];
            pf0[4 + r] = (__bf16)sc[1][r];
            pf1[r]     = (__bf16)sc[2][r];
            pf1[4 + r] = (__bf16)sc[3][r];
        }
        __builtin_amdgcn_s_setprio(1);
#pragma unroll
        for (int dt = 0; dt < 4; ++dt) {
            o[dt] = __builtin_amdgcn_mfma_f32_16x16x32_bf16(pf0, vb0[dt], o[dt], 0, 0, 0);
            o[dt] = __builtin_amdgcn_mfma_f32_16x16x32_bf16(pf1, vb1[dt], o[dt], 0, 0, 0);
        }
        __builtin_amdgcn_s_setprio(0);
    };

    // -------- merge groups 1..3 into group 0, then store q-tile `qt` --------
    auto merge_store = [&](int qt, f32x4* o, float& mprev, float& lsum) {
        // complete the deferred quad-reduction of lsum (once per phase)
        lsum += __shfl_xor(lsum, 16);
        lsum += __shfl_xor(lsum, 32);
        for (int rr = 1; rr < 4; ++rr) {
            __syncthreads();
            if (grp == rr) {
                if (quad == 0) { mx1[wg * 16 + l15] = mprev; lx1[wg * 16 + l15] = lsum; }
#pragma unroll
                for (int dt = 0; dt < 4; ++dt)
#pragma unroll
                    for (int r = 0; r < 4; ++r)
                        xchg[(wg * 16 + quad * 4 + r) * 65 + dt * 16 + l15] = o[dt][r];
            }
            __syncthreads();
            if (grp == 0) {
#pragma unroll
                for (int r = 0; r < 4; ++r) {
                    const int row = wg * 16 + quad * 4 + r;
                    const float m0r = __shfl(mprev, quad * 4 + r);
                    const float m1r = mx1[row];
                    const float ms  = fmaxf(m0r, m1r);
                    const float w0  = EXP2(m0r - ms);
                    const float w1  = EXP2(m1r - ms);
#pragma unroll
                    for (int dt = 0; dt < 4; ++dt)
                        o[dt][r] = o[dt][r] * w0 + xchg[row * 65 + dt * 16 + l15] * w1;
                }
                const float m1l = mx1[wg * 16 + l15];
                const float msl = fmaxf(mprev, m1l);
                lsum = EXP2(mprev - msl) * lsum + EXP2(m1l - msl) * lx1[wg * 16 + l15];
                mprev = msl;
            }
        }
        if (grp == 0) {
            float rl[4];
#pragma unroll
            for (int r = 0; r < 4; ++r) rl[r] = 1.0f / __shfl(lsum, quad * 4 + r);
            const int orow = qt * 64 + wg * 16 + quad * 4;
#pragma unroll
            for (int dt = 0; dt < 4; ++dt)
#pragma unroll
                for (int r = 0; r < 4; ++r)
                    out[(long)(b * TT + orow + r) * HH + dt * 16 + l15] = o[dt][r] * rl[r];
        }
        __syncthreads();   // xchg/mx1 reusable by next phase
    };

    // ---------------- phase A: q-tile 63-p ----------------
    {
        const int qt = 63 - p;
        const int qrow = qt * 64 + wg * 16 + l15;
        const unsigned short* qbase = q_ws + (b * TT + qrow) * HH;
        const bf16x8 qf0 = *reinterpret_cast<const bf16x8*>(qbase + quad * 8);
        const bf16x8 qf1 = *reinterpret_cast<const bf16x8*>(qbase + 32 + quad * 8);
        f32x4 o[4];
#pragma unroll
        for (int dt = 0; dt < 4; ++dt) o[dt] = zero;
        float mprev = -1e30f, lsum = 0.f;
        for (int t = grp; t <= qt; t += 4)
            do_tile(t, qt, qrow, qf0, qf1, o, mprev, lsum);
        merge_store(qt, o, mprev, lsum);
    }

    // ---------------- phase B: q-tile p ----------------
    {
        const int qt = p;
        const int qrow = qt * 64 + wg * 16 + l15;
        const unsigned short* qbase = q_ws + (b * TT + qrow) * HH;
        const bf16x8 qf0 = *reinterpret_cast<const bf16x8*>(qbase + quad * 8);
        const bf16x8 qf1 = *reinterpret_cast<const bf16x8*>(qbase + 32 + quad * 8);
        f32x4 o[4];
#pragma unroll
        for (int dt = 0; dt < 4; ++dt) o[dt] = zero;
        float mprev = -1e30f, lsum = 0.f;
        for (int t = grp; t <= qt; t += 4)
            do_tile(t, qt, qrow, qf0, qf1, o, mprev, lsum);
        merge_store(qt, o, mprev, lsum);
    }
}

// ---------------------------------------------------------------- launch
extern "C" void kernel_launch(void* const* d_in, const int* in_sizes, int n_in,
                              void* d_out, int out_size, void* d_ws, size_t ws_size,
                              hipStream_t stream) {
    const float* x  = (const float*)d_in[0];
    const float* Wk = (const float*)d_in[1];
    const float* Wq = (const float*)d_in[2];
    const float* Wv = (const float*)d_in[3];
    float* out = (float*)d_out;

    char* ws = (char*)d_ws;
    unsigned short* Wt    = (unsigned short*)(ws);                         // 147456 B
    unsigned short* q_ws  = (unsigned short*)(ws + 147456);                // 4 MiB
    unsigned short* k_ws  = (unsigned short*)(ws + 147456 + 4194304);      // 4 MiB
    unsigned short* vt_ws = (unsigned short*)(ws + 147456 + 2 * 4194304);  // 4 MiB

    wtrans_kernel<<<dim3(6, 3), 256, 0, stream>>>(Wk, Wq, Wv, Wt);
    qkv_kernel<<<NROW / 32, 256, 0, stream>>>(x, Wt, q_ws, k_ws, vt_ws);
    attn_kernel<<<(TT / 128) * BB, 1024, 0, stream>>>(q_ws, k_ws, vt_ws, out);
}

// Round 14
// 139.181 us; speedup vs baseline: 1.6524x; 1.1506x over previous
//
#include <hip/hip_runtime.h>
#include <hip/hip_bf16.h>

// B=8, T=4096, C=384, H=64 causal single-head attention. fp32 in/out.
//
// Round-26: qkv Wt-via-LDS (the one untested config). r25 reproduced the
// baseline (160.15us; attn 45.5 frozen, qkv 46.0). All SIX failed qkv
// variants shared one property: Wt consumed from GLOBAL by VGPR loads --
// and r18/r22 proved the compiler refuses the ~96-reg pipeline (VGPR stuck
// 68->88, loads rematerialized), leaving a ~60-deep dependent L2 chain per
// wave (~10us/block x 4 rounds = the 46us invariant). Fix = textbook §5:
// stage BOTH operands by zero-register global_load_lds DMA, consume both
// from LDS. Per 64-col chunk: Wt[3][64][64] bf16 = 24.5KB dbuf + x 8KB
// dbuf; inner loop is pure ds_read->MFMA (counted lgkmcnt, the proven
// path). LDS 70.7KB -> 2 blocks/CU so per-chunk vmcnt(0)+barrier drains
// overlap across blocks. Wt LDS rows are 128B (stride-128 conflict on the
// nt-column read) -> m173 swizzle pair: DMA source chunk c8 ^ (h&7), same
// XOR on the ds_read. attn/wtrans byte-identical to r25.
// Gates: qkv VGPR ~50-64, LDS 70656, FETCH ~25MB, WRITE ~12MB.
//
//  k_frag layout: [blk64][st][c8=h/8][i=m][j=h%8], row m of st holds
//                 K row s = 32*(st>>1) + 8*(m>>2) + 4*(st&1) + (m&3)
//  vt_frag layout: [st=row/64][dt=d/16][sc=s%64/8][i=d%16][j=s%8]

typedef __bf16 bf16x8 __attribute__((ext_vector_type(8)));
typedef float  f32x4  __attribute__((ext_vector_type(4)));

#define BB   8
#define TT   4096
#define CC   384
#define HH   64
#define NROW (BB*TT)       // 32768
// C^-0.5 * log2(e): fold softmax scale + exp2 conversion into q at projection
#define QSCALE (0.05103103630798288f * 1.4426950408889634f)

#if __has_builtin(__builtin_amdgcn_exp2f)
#define EXP2(x) __builtin_amdgcn_exp2f(x)
#else
#define EXP2(x) exp2f(x)
#endif

__device__ __forceinline__ unsigned short f2bf(float f) {
    __bf16 h = (__bf16)f;
    return __builtin_bit_cast(unsigned short, h);
}

// ---------------------------------------------------------------- kernel 1
// Wt[mat][h][c] = bf16(W[mat][c][h]), via LDS tile (coalesced both sides).
__global__ __launch_bounds__(256) void wtrans_kernel(
        const float* __restrict__ Wk,
        const float* __restrict__ Wq,
        const float* __restrict__ Wv,
        unsigned short* __restrict__ Wt) {
    __shared__ __align__(16) unsigned short tile[64][72];
    const float* Wm = (blockIdx.y == 0) ? Wk : ((blockIdx.y == 1) ? Wq : Wv);
    unsigned short* Wtm = Wt + blockIdx.y * (HH * CC);
    const int c0 = blockIdx.x * 64;
#pragma unroll
    for (int i = 0; i < 16; ++i) {
        int id = threadIdx.x + i * 256;         // 0..4095
        int c = id >> 6, h = id & 63;
        tile[c][h] = f2bf(Wm[(c0 + c) * HH + h]);   // coalesced read
    }
    __syncthreads();
#pragma unroll
    for (int i = 0; i < 16; ++i) {
        int id = threadIdx.x + i * 256;
        int h = id >> 6, c = id & 63;
        Wtm[h * CC + c0 + c] = tile[c][h];      // coalesced write
    }
}

// ---------------------------------------------------------------- kernel 2
// QKV projection: [32768,384]x[384,64] x3 with 16x16x32 bf16 MFMA.
// 1024 blocks x 256 thr; block = 32 rows. 4 waves = 2 row-tiles x 2 h-halves.
// BOTH operands staged by global_load_lds DMA per 64-col chunk (dbuf):
//   x chunk  -> xs2[2][32][64] fp32 (source-swizzled ch ^ (row&7))
//   Wt chunk -> wts[2][3][64][64] bf16 (source-swizzled c8 ^ (h&7))
// Inner loop is pure LDS->MFMA. One vmcnt(0)+barrier per chunk; 2 blocks/CU
// co-resident overlap the drains. Epilogue layouts identical to round-15.
__global__ __launch_bounds__(256, 1) void qkv_kernel(
        const float* __restrict__ x,
        const unsigned short* __restrict__ Wt,     // [3][64][384] bf16
        unsigned short* __restrict__ q_ws,         // [32768][64] row-major, pre-scaled
        unsigned short* __restrict__ k_ws,         // fragment layout (permuted)
        unsigned short* __restrict__ vt_ws) {      // fragment layout
    __shared__ __align__(16) float xs2[2][32][64];              // 16384 B
    __shared__ __align__(16) unsigned short wts[2][3][64][64];  // 49152 B
    __shared__ __align__(16) unsigned short vtile[64][40];      //  5120 B

    const int lane = threadIdx.x & 63;
    const int wv   = threadIdx.x >> 6;     // 0..3
    const int rt   = wv & 1;               // row-tile (16 rows)
    const int hh   = wv >> 1;              // h-half (2 nt)
    const int l15  = lane & 15;
    const int quad = lane >> 4;
    const int rb   = blockIdx.x * 32;
    const int ntb  = hh * 2;               // first of this wave's two nt

    // ---- DMA one 64-col x chunk into xs2[bb] (2 instrs/wave) ----
    auto stageX = [&](int kk, int bb) {
#pragma unroll
        for (int j = 0; j < 2; ++j) {
            const int r0 = wv * 8 + j * 4;                 // instr's first row
            const int r  = r0 + quad;                      // this lane's row
            const int ch = l15 ^ (r & 7);                  // swizzled src chunk
            const float* src = x + (long)(rb + r) * CC + kk * 64 + ch * 4;
            float* dst = &xs2[bb][r0][0];                  // linear: +lane*16B
            __builtin_amdgcn_global_load_lds(
                (const __attribute__((address_space(1))) unsigned int*)src,
                (__attribute__((address_space(3))) unsigned int*)dst,
                16, 0, 0);
        }
    };

    // ---- DMA one 64-col Wt chunk [3][64][64] into wts[bb] (6 instrs/wave) --
    // instr j covers mat m = j/8, rows rg*8..rg*8+7; lane l -> row rg*8+(l>>3),
    // 16B slot (l&7); source chunk pre-swizzled (c8 ^ (h&7)).
    auto stageW = [&](int kk, int bb) {
#pragma unroll
        for (int i = 0; i < 6; ++i) {
            const int j   = wv + 4 * i;                    // 0..23
            const int m   = j >> 3;                        // 0..2
            const int rg  = j & 7;                         // row-group
            const int h   = rg * 8 + (lane >> 3);          // this lane's row
            const int chs = (lane & 7) ^ (h & 7);          // swizzled src chunk
            const unsigned short* src =
                Wt + m * (HH * CC) + h * CC + kk * 64 + chs * 8;
            unsigned short* dst = &wts[bb][m][rg * 8][0];  // linear: +lane*16B
            __builtin_amdgcn_global_load_lds(
                (const __attribute__((address_space(1))) unsigned int*)src,
                (__attribute__((address_space(3))) unsigned int*)dst,
                16, 0, 0);
        }
    };

    f32x4 acc[3][2];
    const f32x4 zero = {0.f, 0.f, 0.f, 0.f};
#pragma unroll
    for (int m = 0; m < 3; ++m)
#pragma unroll
        for (int n = 0; n < 2; ++n) acc[m][n] = zero;

    const int rloc = rt * 16 + l15;        // A-frag row (local)
    const int rx7  = rloc & 7;
    const int hx7  = l15 & 7;              // Wt read swizzle (h&7 == l15&7)

    stageX(0, 0);
    stageW(0, 0);
    __asm volatile("s_waitcnt vmcnt(0)" ::: "memory");
    __syncthreads();

#pragma unroll
    for (int kk = 0; kk < 6; ++kk) {
        const int cur = kk & 1;
        if (kk < 5) { stageX(kk + 1, cur ^ 1); stageW(kk + 1, cur ^ 1); }
#pragma unroll
        for (int h01 = 0; h01 < 2; ++h01) {
            const int chb = 8 * h01 + 2 * quad;
            const f32x4 xa = *reinterpret_cast<const f32x4*>(
                &xs2[cur][rloc][((chb) ^ rx7) * 4]);
            const f32x4 xb = *reinterpret_cast<const f32x4*>(
                &xs2[cur][rloc][((chb + 1) ^ rx7) * 4]);
            bf16x8 a;
#pragma unroll
            for (int e = 0; e < 4; ++e) {
                a[e]     = (__bf16)xa[e];
                a[4 + e] = (__bf16)xb[e];
            }
#pragma unroll
            for (int m = 0; m < 3; ++m)
#pragma unroll
                for (int n = 0; n < 2; ++n) {
                    const int hN = (ntb + n) * 16 + l15;
                    const bf16x8 bfr = *reinterpret_cast<const bf16x8*>(
                        &wts[cur][m][hN][(((h01 << 2) + quad) ^ hx7) << 3]);
                    acc[m][n] = __builtin_amdgcn_mfma_f32_16x16x32_bf16(
                        a, bfr, acc[m][n], 0, 0, 0);
                }
        }
        __asm volatile("s_waitcnt vmcnt(0)" ::: "memory");
        __syncthreads();
    }

    // Epilogue. C-layout: acc[m][n][r] = out[local row quad*4+r][h=(ntb+n)*16+l15]
#pragma unroll
    for (int n = 0; n < 2; ++n) {
        const int nt = ntb + n;
        const int h  = nt * 16 + l15;
        const int c8 = h >> 3;
        const int jj = h & 7;
#pragma unroll
        for (int r = 0; r < 4; ++r) {
            const int gr = rb + rt * 16 + quad * 4 + r;
            // k: permuted fragment position for local row s = gr & 63
            const int s   = gr & 63;
            const int stp = ((s >> 4) & 2) + ((s >> 2) & 1); // 2*(s>>5)+bit2
            const int ip  = ((s >> 1) & 12) + (s & 3);       // 4*((s>>3)&3)+(s&3)
            k_ws[(long)(gr >> 6) * 4096 + stp * 1024 + c8 * 128 + ip * 8 + jj]
                = f2bf(acc[0][n][r]);
            q_ws[gr * HH + h] = f2bf(acc[1][n][r] * QSCALE);
            vtile[h][rt * 16 + quad * 4 + r] = f2bf(acc[2][n][r]);
        }
    }
    __syncthreads();
    // vt fragment store: block covers sc-half (rb&32)>>3 of its 64-blk.
    {
        const int id  = threadIdx.x;               // 0..255
        const int dt  = id >> 6, scl = (id >> 4) & 3, ii = id & 15;
        const int sc  = scl + ((rb >> 3) & 4);
        unsigned short* dst = vt_ws + (long)(rb >> 6) * 4096
                              + (dt * 8 + sc) * 128 + ii * 8;
        *reinterpret_cast<uint4*>(dst) =
            *reinterpret_cast<const uint4*>(&vtile[dt * 16 + ii][scl * 8]);
    }
}

// ---------------------------------------------------------------- kernel 3
// Flash attention (frozen at r22/r25 best). 256 blocks x 1024 thr; block
// (p,b) does q-tile A=63-p then B=p (65 k-tiles constant). 16 waves = 4
// groups x 4 waves; group g takes tiles t = 4j+g. Barrier-free k-loop, P
// entirely in registers (k_frag row permutation makes QK output == PV
// A-fragment). Softmax: defer-max (THR=8); lsum per-quad, reduced at merge
// entry. s_setprio(1) around QK/PV MFMA clusters.
__global__ __launch_bounds__(1024, 4) void attn_kernel(
        const unsigned short* __restrict__ q_ws,
        const unsigned short* __restrict__ k_ws,   // permuted fragment layout
        const unsigned short* __restrict__ vt_ws,  // fragment layout
        float* __restrict__ out) {
    __shared__ __align__(16) float xchg[64 * 65];                // 16640 B
    __shared__ float mx1[64], lx1[64];

    const int lane = threadIdx.x & 63;
    const int wv16 = threadIdx.x >> 6;     // 0..15
    const int grp  = wv16 >> 2;            // wave-group 0..3
    const int wg   = wv16 & 3;             // wave within group
    const int l15  = lane & 15;
    const int quad = lane >> 4;

    const int bid = blockIdx.x;
    const int b   = bid & 7;               // batch <-> XCD affinity
    const int p   = bid >> 3;              // 0..31

    const f32x4 zero = {0.f, 0.f, 0.f, 0.f};

    // -------- one k-tile of phase with q-tile `qt` --------
    auto do_tile = [&](int t, int qt, int qrow,
                       const bf16x8& qf0, const bf16x8& qf1,
                       f32x4* o, float& mprev, float& lsum) {
        const int s0 = t * 64;
        const unsigned short* ktile = k_ws + ((long)((b * TT + s0) >> 4)) * 1024;
        const unsigned short* vtile = vt_ws + ((long)((b * TT + s0) >> 6)) * 4096;

        bf16x8 ka0[4], ka1[4];
#pragma unroll
        for (int st = 0; st < 4; ++st) {
            ka0[st] = *reinterpret_cast<const bf16x8*>(
                ktile + ((st * 8 + quad) * 16 + l15) * 8);
            ka1[st] = *reinterpret_cast<const bf16x8*>(
                ktile + ((st * 8 + 4 + quad) * 16 + l15) * 8);
        }
        bf16x8 vb0[4], vb1[4];
#pragma unroll
        for (int dt = 0; dt < 4; ++dt) {
            vb0[dt] = *reinterpret_cast<const bf16x8*>(
                vtile + dt * 1024 + quad * 128 + l15 * 8);
            vb1[dt] = *reinterpret_cast<const bf16x8*>(
                vtile + dt * 1024 + (4 + quad) * 128 + l15 * 8);
        }

        f32x4 sc[4];
        __builtin_amdgcn_s_setprio(1);
#pragma unroll
        for (int st = 0; st < 4; ++st) {
            f32x4 z = zero;
            z = __builtin_amdgcn_mfma_f32_16x16x32_bf16(ka0[st], qf0, z, 0, 0, 0);
            z = __builtin_amdgcn_mfma_f32_16x16x32_bf16(ka1[st], qf1, z, 0, 0, 0);
            sc[st] = z;
        }
        __builtin_amdgcn_s_setprio(0);

        if (t == qt) {                    // causal mask, diagonal tile only
            // permuted row map: s_local = 32*(st>>1) + 8*quad + 4*(st&1) + r
#pragma unroll
            for (int st = 0; st < 4; ++st)
#pragma unroll
                for (int r = 0; r < 4; ++r) {
                    int sg = s0 + ((st >> 1) << 5) + (quad << 3)
                               + ((st & 1) << 2) + r;
                    if (sg > qrow) sc[st][r] = -1e30f;
                }
        }

        float mloc = -1e30f;
#pragma unroll
        for (int st = 0; st < 4; ++st)
#pragma unroll
            for (int r = 0; r < 4; ++r) mloc = fmaxf(mloc, sc[st][r]);
        mloc = fmaxf(mloc, __shfl_xor(mloc, 16));
        mloc = fmaxf(mloc, __shfl_xor(mloc, 32));

        // defer-max: keep old max when the tile max is within THR=8
        // (exp2 domain; P bounded by 2^8=256, bf16/fp32-safe).
        if (!__all(mloc <= mprev + 8.0f)) {
            const float mnew = fmaxf(mprev, mloc);
            const float alpha = EXP2(mprev - mnew);
            lsum *= alpha;
            float ar[4];
#pragma unroll
            for (int r = 0; r < 4; ++r) ar[r] = __shfl(alpha, quad * 4 + r);
#pragma unroll
            for (int dt = 0; dt < 4; ++dt)
#pragma unroll
                for (int r = 0; r < 4; ++r) o[dt][r] *= ar[r];
            mprev = mnew;
        }

        // exp2 against (possibly stale) mprev; lsum stays per-quad partial.
        float psum = 0.f;
#pragma unroll
        for (int st = 0; st < 4; ++st)
#pragma unroll
            for (int r = 0; r < 4; ++r) {
                float pv = EXP2(sc[st][r] - mprev);
                psum += pv;
                sc[st][r] = pv;
            }
        lsum += psum;

        // P in-register: sc[st][r] already in PV A-fragment order.
        bf16x8 pf0, pf1;
#pragma unroll
        for (int r = 0; r < 4; ++r) {
            pf0[r]     = (__bf16)sc[0][r];
            pf0[4 + r] = (__bf16)sc[1][r];
            pf1[r]     = (__bf16)sc[2][r];
            pf1[4 + r] = (__bf16)sc[3][r];
        }
        __builtin_amdgcn_s_setprio(1);
#pragma unroll
        for (int dt = 0; dt < 4; ++dt) {
            o[dt] = __builtin_amdgcn_mfma_f32_16x16x32_bf16(pf0, vb0[dt], o[dt], 0, 0, 0);
            o[dt] = __builtin_amdgcn_mfma_f32_16x16x32_bf16(pf1, vb1[dt], o[dt], 0, 0, 0);
        }
        __builtin_amdgcn_s_setprio(0);
    };

    // -------- merge groups 1..3 into group 0, then store q-tile `qt` --------
    auto merge_store = [&](int qt, f32x4* o, float& mprev, float& lsum) {
        // complete the deferred quad-reduction of lsum (once per phase)
        lsum += __shfl_xor(lsum, 16);
        lsum += __shfl_xor(lsum, 32);
        for (int rr = 1; rr < 4; ++rr) {
            __syncthreads();
            if (grp == rr) {
                if (quad == 0) { mx1[wg * 16 + l15] = mprev; lx1[wg * 16 + l15] = lsum; }
#pragma unroll
                for (int dt = 0; dt < 4; ++dt)
#pragma unroll
                    for (int r = 0; r < 4; ++r)
                        xchg[(wg * 16 + quad * 4 + r) * 65 + dt * 16 + l15] = o[dt][r];
            }
            __syncthreads();
            if (grp == 0) {
#pragma unroll
                for (int r = 0; r < 4; ++r) {
                    const int row = wg * 16 + quad * 4 + r;
                    const float m0r = __shfl(mprev, quad * 4 + r);
                    const float m1r = mx1[row];
                    const float ms  = fmaxf(m0r, m1r);
                    const float w0  = EXP2(m0r - ms);
                    const float w1  = EXP2(m1r - ms);
#pragma unroll
                    for (int dt = 0; dt < 4; ++dt)
                        o[dt][r] = o[dt][r] * w0 + xchg[row * 65 + dt * 16 + l15] * w1;
                }
                const float m1l = mx1[wg * 16 + l15];
                const float msl = fmaxf(mprev, m1l);
                lsum = EXP2(mprev - msl) * lsum + EXP2(m1l - msl) * lx1[wg * 16 + l15];
                mprev = msl;
            }
        }
        if (grp == 0) {
            float rl[4];
#pragma unroll
            for (int r = 0; r < 4; ++r) rl[r] = 1.0f / __shfl(lsum, quad * 4 + r);
            const int orow = qt * 64 + wg * 16 + quad * 4;
#pragma unroll
            for (int dt = 0; dt < 4; ++dt)
#pragma unroll
                for (int r = 0; r < 4; ++r)
                    out[(long)(b * TT + orow + r) * HH + dt * 16 + l15] = o[dt][r] * rl[r];
        }
        __syncthreads();   // xchg/mx1 reusable by next phase
    };

    // ---------------- phase A: q-tile 63-p ----------------
    {
        const int qt = 63 - p;
        const int qrow = qt * 64 + wg * 16 + l15;
        const unsigned short* qbase = q_ws + (b * TT + qrow) * HH;
        const bf16x8 qf0 = *reinterpret_cast<const bf16x8*>(qbase + quad * 8);
        const bf16x8 qf1 = *reinterpret_cast<const bf16x8*>(qbase + 32 + quad * 8);
        f32x4 o[4];
#pragma unroll
        for (int dt = 0; dt < 4; ++dt) o[dt] = zero;
        float mprev = -1e30f, lsum = 0.f;
        for (int t = grp; t <= qt; t += 4)
            do_tile(t, qt, qrow, qf0, qf1, o, mprev, lsum);
        merge_store(qt, o, mprev, lsum);
    }

    // ---------------- phase B: q-tile p ----------------
    {
        const int qt = p;
        const int qrow = qt * 64 + wg * 16 + l15;
        const unsigned short* qbase = q_ws + (b * TT + qrow) * HH;
        const bf16x8 qf0 = *reinterpret_cast<const bf16x8*>(qbase + quad * 8);
        const bf16x8 qf1 = *reinterpret_cast<const bf16x8*>(qbase + 32 + quad * 8);
        f32x4 o[4];
#pragma unroll
        for (int dt = 0; dt < 4; ++dt) o[dt] = zero;
        float mprev = -1e30f, lsum = 0.f;
        for (int t = grp; t <= qt; t += 4)
            do_tile(t, qt, qrow, qf0, qf1, o, mprev, lsum);
        merge_store(qt, o, mprev, lsum);
    }
}

// ---------------------------------------------------------------- launch
extern "C" void kernel_launch(void* const* d_in, const int* in_sizes, int n_in,
                              void* d_out, int out_size, void* d_ws, size_t ws_size,
                              hipStream_t stream) {
    const float* x  = (const float*)d_in[0];
    const float* Wk = (const float*)d_in[1];
    const float* Wq = (const float*)d_in[2];
    const float* Wv = (const float*)d_in[3];
    float* out = (float*)d_out;

    char* ws = (char*)d_ws;
    unsigned short* Wt    = (unsigned short*)(ws);                         // 147456 B
    unsigned short* q_ws  = (unsigned short*)(ws + 147456);                // 4 MiB
    unsigned short* k_ws  = (unsigned short*)(ws + 147456 + 4194304);      // 4 MiB
    unsigned short* vt_ws = (unsigned short*)(ws + 147456 + 2 * 4194304);  // 4 MiB

    wtrans_kernel<<<dim3(6, 3), 256, 0, stream>>>(Wk, Wq, Wv, Wt);
    qkv_kernel<<<NROW / 32, 256, 0, stream>>>(x, Wt, q_ws, k_ws, vt_ws);
    attn_kernel<<<(TT / 128) * BB, 1024, 0, stream>>>(q_ws, k_ws, vt_ws, out);
}